// Round 7
// baseline (348.229 us; speedup 1.0000x reference)
//
#include <hip/hip_runtime.h>
#include <stdint.h>

// CustomLSTMCell: B=4096, I=512, H=1024, fp32 in/out.
// R6: B direct-to-register. R2-R4 invariance at ~142us + cycle accounting shows
// the LDS data port ~87% busy (reads 1152 + staging writes 384 per block-K-step
// vs MFMA 1242): LDS-PORT-BOUND. B has zero cross-wave reuse (wave owns its
// gate matrix) -> staging B through LDS was pure port overhead. Now B frags are
// per-lane global loads (reg double-buffered); A keeps gload_lds 3-deep + T2
// swizzle (A has 4x cross-wave reuse). LDS 144->69.6KB. W stored LINEAR in ws.
// R5's 256-row shape discarded: acc 256+64 regs > 256-reg cap (would spill).
// c_temp (d_in[4]) is dead in the reference.

#define B_DIM 4096
#define I_DIM 512
#define H_DIM 1024
#define K_DIM 1536
#define NK 48              // K-steps of 32
#define ABUFB (16 * 1024)  // per A pipeline buffer: [2 br][128 rows][64 B]

typedef __attribute__((ext_vector_type(8))) __bf16 bf16x8;
typedef __attribute__((ext_vector_type(4))) float f32x4;
typedef __attribute__((ext_vector_type(4))) uint32_t u32x4;

static __device__ __forceinline__ uint32_t f2bf(float f) {
  uint32_t u = __builtin_bit_cast(uint32_t, f);
  return (u + 0x7FFFu + ((u >> 16) & 1u)) >> 16;  // RNE (inputs finite)
}
static __device__ __forceinline__ uint32_t pack2(float lo, float hi) {
  return f2bf(lo) | (f2bf(hi) << 16);
}
static __device__ __forceinline__ float sigf(float x) {
  return 1.f / (1.f + __expf(-x));
}
static __device__ __forceinline__ float tanhfast(float x) {
  float t = __expf(fminf(2.f * x, 80.f));
  return (t - 1.f) / (t + 1.f);
}

// ---------------- conversion: fp32 -> bf16 ----------------
// A rows (hx) pre-swizzled for LDS-staged reads; W rows stored LINEAR
// (B is now consumed by direct per-lane global loads, k-contiguous).
__global__ __launch_bounds__(192) void convert_kernel(
    const float* __restrict__ y, const float* __restrict__ h_light,
    const float* __restrict__ h_temp,
    const float* __restrict__ w0, const float* __restrict__ w1,
    const float* __restrict__ w2, const float* __restrict__ w3,
    const float* __restrict__ w4, const float* __restrict__ w5,
    const float* __restrict__ w6, const float* __restrict__ w7,
    uint16_t* __restrict__ ws)
{
  const int row_all = blockIdx.x;     // 0..16383: [2][4096] A rows then [8][1024] W rows
  const int cs = threadIdx.x;         // stored chunk 0..191
  const float* src;
  int cl;                             // logical chunk
  if (row_all < 2 * B_DIM) {
    cl = (cs & ~3) | ((cs & 3) ^ ((row_all >> 1) & 3));  // T2 pre-swizzle (A only)
    const int k0 = cl * 8;
    const int branch = row_all >> 12;
    const int row = row_all & (B_DIM - 1);
    const float* hb = branch ? h_temp : h_light;
    src = (k0 < H_DIM) ? (hb + (size_t)row * H_DIM + k0)
                       : (y + (size_t)row * I_DIM + (k0 - H_DIM));
  } else {
    cl = cs;                                             // linear (W)
    const int ra = row_all - 2 * B_DIM;
    const int mat = ra >> 10;
    const int row = ra & (H_DIM - 1);
    const float* w = (mat < 4) ? ((mat < 2) ? (mat == 0 ? w0 : w1) : (mat == 2 ? w2 : w3))
                               : ((mat < 6) ? (mat == 4 ? w4 : w5) : (mat == 6 ? w6 : w7));
    src = w + (size_t)row * K_DIM + cl * 8;
  }
  f32x4 v0 = *(const f32x4*)src;
  f32x4 v1 = *(const f32x4*)(src + 4);
  u32x4 o;
  o[0] = pack2(v0[0], v0[1]);
  o[1] = pack2(v0[2], v0[3]);
  o[2] = pack2(v1[0], v1[1]);
  o[3] = pack2(v1[2], v1[3]);
  *(u32x4*)(ws + ((size_t)row_all * 192 + cs) * 8) = o;
}

// ---------------- fused 8-matrix GEMM + LSTM epilogue ----------------
// 512 blocks, 512 threads = 8 waves; wave w owns mat w (128 rows x 64 cols).
// A: LDS 3-deep pipeline (gload_lds, T2 swizzle). B: per-lane global loads,
// register double-buffered. One barrier + one vmcnt(6) per K-step.
__global__ __launch_bounds__(512, 2) void lstm_fused_kernel(
    const uint16_t* __restrict__ ws,
    const float* __restrict__ c_light,
    const float* __restrict__ bf1, const float* __restrict__ bi1,
    const float* __restrict__ bc1, const float* __restrict__ bo1,
    const float* __restrict__ bf2, const float* __restrict__ bi2,
    const float* __restrict__ bc2, const float* __restrict__ bo2,
    float* __restrict__ out)
{
  __shared__ alignas(128) char smem[69632];  // A: 3 x 16KB; epilogue zst: 69.6KB

  const int tid = threadIdx.x;
  const int lane = tid & 63;
  const int wv = tid >> 6;

  // bn-major XCD clustering (bijective over 512): xcd owns 2 bn-groups
  const int bid = blockIdx.x;
  const int xcd = bid & 7;
  const int slot = bid >> 3;                 // 0..63
  const int bm0 = (slot & 31) * 128;
  const int bn0 = (xcd * 2 + (slot >> 5)) * 64;

  const uint16_t* wsA = ws;
  const uint16_t* wsW = ws + (size_t)2 * B_DIM * K_DIM;

  const int rA = lane & 15;
  const int kg = lane >> 4;
  // A frag byte offset within a [rows][64B] pane, T2-swizzled chunk
  const uint32_t fo = (uint32_t)rA * 64u + (uint32_t)(kg ^ ((rA >> 1) & 3)) * 16u;
  const uint32_t aoff = (uint32_t)(wv >> 2) * 8192u + fo;   // branch pane

  // A staging sources: chunk c = i*512+tid: br=c>>9, row=(c>>2)&127, cc=c&3
  const uint16_t* sA[2];
  uint32_t ldA[2];
#pragma unroll
  for (int i = 0; i < 2; ++i) {
    int c = i * 512 + tid;
    sA[i] = wsA + (size_t)(c >> 9) * ((size_t)B_DIM * K_DIM) +
            (size_t)(bm0 + ((c >> 2) & 127)) * K_DIM + (c & 3) * 8;
    ldA[i] = (uint32_t)c * 16u;
  }

  // B frag pointers: lane (rA, kg) reads 16B at [bn0+n*16+rA] row, k = kt*32+kg*8
  const uint16_t* pB[4];
#pragma unroll
  for (int n = 0; n < 4; ++n)
    pB[n] = wsW + (size_t)wv * ((size_t)H_DIM * K_DIM) +
            (size_t)(bn0 + n * 16 + rA) * K_DIM + kg * 8;

#define ISSUE(srcp, ldsoff, buf)                                             \
  __builtin_amdgcn_global_load_lds(                                          \
      (const __attribute__((address_space(1))) void*)(srcp),                 \
      (__attribute__((address_space(3))) void*)(smem + (buf)*ABUFB + (ldsoff)), \
      16, 0, 0)

  f32x4 acc[8][4];
#pragma unroll
  for (int m = 0; m < 8; ++m)
#pragma unroll
    for (int n = 0; n < 4; ++n) acc[m][n] = (f32x4){0.f, 0.f, 0.f, 0.f};

  // ---- prologue: A(0), A(1) staged; B(0) into regs ----
  ISSUE(sA[0], ldA[0], 0); ISSUE(sA[1], ldA[1], 0);
  ISSUE(sA[0] + 32, ldA[0], 1); ISSUE(sA[1] + 32, ldA[1], 1);
  sA[0] += 64; sA[1] += 64;
  asm volatile("" ::: "memory");   // pin: A-ISSUEs before B loads (vmcnt ledger)
  bf16x8 Bcur[4], Bnxt[4];
#pragma unroll
  for (int n = 0; n < 4; ++n) { Bcur[n] = *(const bf16x8*)pB[n]; pB[n] += 32; }

  for (int kt = 0; kt < NK; ++kt) {
    // target A(kt): exactly B(kt)x4 + A(kt+1)x2 = 6 vmem ops after it
    if (kt < NK - 1) asm volatile("s_waitcnt vmcnt(6)" ::: "memory");
    else             asm volatile("s_waitcnt vmcnt(0)" ::: "memory");
    __builtin_amdgcn_s_barrier();   // all waves' kt-1 ds_reads complete

    const char* As = smem + (kt % 3) * ABUFB + aoff;
    bf16x8 Af[8];
#pragma unroll
    for (int m = 0; m < 8; ++m) Af[m] = *(const bf16x8*)(As + m * 1024);

    if (kt + 1 < NK) {              // B(kt+1) -> regs (compiler auto-waits uses)
#pragma unroll
      for (int n = 0; n < 4; ++n) { Bnxt[n] = *(const bf16x8*)pB[n]; pB[n] += 32; }
    } else {
#pragma unroll
      for (int n = 0; n < 4; ++n) Bnxt[n] = Bcur[n];
    }
    asm volatile("" ::: "memory");  // pin: B loads before A ISSUEs
    if (kt + 2 < NK) {              // A(kt+2) into buf[(kt+2)%3]
      const int tg3 = (kt + 2) % 3;
      ISSUE(sA[0], ldA[0], tg3); ISSUE(sA[1], ldA[1], tg3);
      sA[0] += 32; sA[1] += 32;
    }

    __builtin_amdgcn_s_setprio(1);
#pragma unroll
    for (int m = 0; m < 8; ++m)
#pragma unroll
      for (int n = 0; n < 4; ++n)
        acc[m][n] = __builtin_amdgcn_mfma_f32_16x16x32_bf16(Af[m], Bcur[n], acc[m][n], 0, 0, 0);
    __builtin_amdgcn_s_setprio(0);
#pragma unroll
    for (int n = 0; n < 4; ++n) Bcur[n] = Bnxt[n];
  }
#undef ISSUE

  // ---- epilogue: 4 chunks of 32 rows through LDS ----
  float* zst = (float*)smem;  // [8 mats][32 rows][68] f32 = 69.6 KB
#pragma unroll
  for (int q = 0; q < 4; ++q) {
    __syncthreads();
#pragma unroll
    for (int mm = 0; mm < 2; ++mm)
#pragma unroll
      for (int n = 0; n < 4; ++n)
#pragma unroll
        for (int j = 0; j < 4; ++j) {
          int r = mm * 16 + kg * 4 + j;  // C/D: row=(l>>4)*4+j, col=l&15
          int c = n * 16 + rA;
          zst[wv * 2176 + r * 68 + c] = acc[q * 2 + mm][n][j];
        }
    __syncthreads();

    int r = tid >> 4;
    int cb = (tid & 15) * 4;
    int grow = bm0 + q * 32 + r;
    int gc = bn0 + cb;
    const float* zb = zst + r * 68 + cb;
    f32x4 z0 = *(const f32x4*)(zb + 0 * 2176) + *(const f32x4*)(bf1 + gc);
    f32x4 z1 = *(const f32x4*)(zb + 1 * 2176) + *(const f32x4*)(bi1 + gc);
    f32x4 z2 = *(const f32x4*)(zb + 2 * 2176) + *(const f32x4*)(bc1 + gc);
    f32x4 z3 = *(const f32x4*)(zb + 3 * 2176) + *(const f32x4*)(bo1 + gc);
    f32x4 z4 = *(const f32x4*)(zb + 4 * 2176) + *(const f32x4*)(bf2 + gc);
    f32x4 z5 = *(const f32x4*)(zb + 5 * 2176) + *(const f32x4*)(bi2 + gc);
    f32x4 z6 = *(const f32x4*)(zb + 6 * 2176) + *(const f32x4*)(bc2 + gc);
    f32x4 z7 = *(const f32x4*)(zb + 7 * 2176) + *(const f32x4*)(bo2 + gc);
    f32x4 cl4 = *(const f32x4*)(c_light + (size_t)grow * H_DIM + gc);
    f32x4 hv, cv;
#pragma unroll
    for (int j = 0; j < 4; ++j) {
      float f1 = sigf(z0[j]);
      float i1 = sigf(z1[j]);
      float ch1 = tanhfast(z2[j]);
      float o1 = sigf(z3[j]);
      float f2 = sigf(z4[j]);
      float i2 = sigf(z5[j]);
      float ch2 = tanhfast(z6[j]);
      float o2 = sigf(z7[j]);
      float cn = f1 * cl4[j] + i1 * ch1 + f2 * cl4[j] + i2 * ch2;
      hv[j] = (o1 + o2) * tanhfast(cn);
      cv[j] = cn;
    }
    *(f32x4*)(out + (size_t)grow * H_DIM + gc) = hv;
    *(f32x4*)(out + (size_t)(B_DIM * H_DIM) + (size_t)grow * H_DIM + gc) = cv;
  }
}

extern "C" void kernel_launch(void* const* d_in, const int* in_sizes, int n_in,
                              void* d_out, int out_size, void* d_ws, size_t ws_size,
                              hipStream_t stream) {
  (void)in_sizes; (void)n_in; (void)out_size; (void)ws_size;
  const float* y       = (const float*)d_in[0];
  const float* h_light = (const float*)d_in[1];
  const float* c_light = (const float*)d_in[2];
  const float* h_temp  = (const float*)d_in[3];
  // d_in[4] = c_temp: dead in the reference computation.
  uint16_t* ws = (uint16_t*)d_ws;  // needs 50,331,648 B

  convert_kernel<<<16384, 192, 0, stream>>>(
      y, h_light, h_temp,
      (const float*)d_in[5],  (const float*)d_in[7],  (const float*)d_in[9],  (const float*)d_in[11],
      (const float*)d_in[13], (const float*)d_in[15], (const float*)d_in[17], (const float*)d_in[19],
      ws);

  lstm_fused_kernel<<<512, 512, 0, stream>>>(
      ws, c_light,
      (const float*)d_in[6],  (const float*)d_in[8],  (const float*)d_in[10], (const float*)d_in[12],
      (const float*)d_in[14], (const float*)d_in[16], (const float*)d_in[18], (const float*)d_in[20],
      (float*)d_out);
}